// Round 1
// baseline (5874.253 us; speedup 1.0000x reference)
//
#include <hip/hip_runtime.h>
#include <math.h>

// WindowAttention (Swin-style), fp32-exact fused kernel.
// x:[4096,49,256] mask:[64,49,49] wq/wk/wv/wo:[256,256] bias_table:[169,8] rel_index:[49,49]
// out:[4096,49,256]
//
// One block per window, 256 threads (4 waves). Per head h:
//   A: q,k,v head projections (thread = output column d of head, ~7 rows each)
//   B: scores (lane = key token) + bias + mask + 64-lane shuffle softmax + PV via readlane
//   C: out_acc[r] += attn_h @ wo[h*32:(h+1)*32, :]   (register accumulators, 49/thread)
// LDS ~25KB static; no workspace needed.

constexpr int L  = 49;
constexpr int C  = 256;
constexpr int NH = 8;
constexpr int DK = 32;
constexpr int KT_STRIDE = 50;   // 50 % 32 = 18, gcd(18,32)=2 -> 2-way bank aliasing (free)

__global__ __launch_bounds__(256)
void winattn_fused(const float* __restrict__ x,  const float* __restrict__ msk,
                   const float* __restrict__ wq, const float* __restrict__ wk,
                   const float* __restrict__ wvw,const float* __restrict__ wo,
                   const float* __restrict__ bt, const int* __restrict__ ri,
                   float* __restrict__ out)
{
    __shared__ float kTh[DK * KT_STRIDE]; // k^T for head: [DK][50]
    __shared__ float qh [L * DK];         // q for head:   [49][32]
    __shared__ float vh [L * DK];         // v for head:   [49][32]
    __shared__ float ah [L * DK];         // attn out:     [49][32]

    const int t    = threadIdx.x;
    const int w    = blockIdx.x;
    const int lane = t & 63;
    const int wid  = t >> 6;   // wave id 0..3
    const int d    = t & 31;   // head-dim column this thread owns
    const int g    = t >> 5;   // row group 0..7

    const float* __restrict__ xg = x   + (size_t)w * (L * C);
    const float* __restrict__ mg = msk + (size_t)(w & 63) * (L * L); // window-in-image = w % 64

    float oacc[L];
    #pragma unroll
    for (int r = 0; r < L; ++r) oacc[r] = 0.0f;

    for (int h = 0; h < NH; ++h) {
        // ---------------- Phase A: q,k,v projection for head h ----------------
        float qA[7], kA[7], vA[7];
        #pragma unroll
        for (int i = 0; i < 7; ++i) { qA[i] = 0.0f; kA[i] = 0.0f; vA[i] = 0.0f; }
        const int hd = h * DK + d;

        for (int c = 0; c < C; c += 4) {
            const float* wqp = wq  + (size_t)c * C + hd;
            const float* wkp = wk  + (size_t)c * C + hd;
            const float* wvp = wvw + (size_t)c * C + hd;
            const float q0 = wqp[0], q1 = wqp[C], q2 = wqp[2 * C], q3 = wqp[3 * C];
            const float k0 = wkp[0], k1 = wkp[C], k2 = wkp[2 * C], k3 = wkp[3 * C];
            const float v0 = wvp[0], v1 = wvp[C], v2 = wvp[2 * C], v3 = wvp[3 * C];
            #pragma unroll
            for (int i = 0; i < 7; ++i) {
                const int r = g + 8 * i;
                if (r < L) {
                    const float4 xv = *reinterpret_cast<const float4*>(xg + r * C + c);
                    qA[i] = fmaf(xv.x, q0, fmaf(xv.y, q1, fmaf(xv.z, q2, fmaf(xv.w, q3, qA[i]))));
                    kA[i] = fmaf(xv.x, k0, fmaf(xv.y, k1, fmaf(xv.z, k2, fmaf(xv.w, k3, kA[i]))));
                    vA[i] = fmaf(xv.x, v0, fmaf(xv.y, v1, fmaf(xv.z, v2, fmaf(xv.w, v3, vA[i]))));
                }
            }
        }
        #pragma unroll
        for (int i = 0; i < 7; ++i) {
            const int r = g + 8 * i;
            if (r < L) {
                qh [r * DK + d]        = qA[i];
                kTh[d * KT_STRIDE + r] = kA[i];
                vh [r * DK + d]        = vA[i];
            }
        }
        __syncthreads();

        // ---------------- Phase B: scores + softmax + PV ----------------
        const int lc = (lane < L) ? lane : 0;      // clamped key-token index
        float kreg[DK];
        #pragma unroll
        for (int dd = 0; dd < DK; ++dd) kreg[dd] = kTh[dd * KT_STRIDE + lc];

        for (int i = 0; i < 13; ++i) {
            const int r = wid + 4 * i;             // q row owned by this wave
            if (r >= L) break;                     // wave-uniform exit, no barriers inside
            float s = 0.0f;
            #pragma unroll
            for (int dd = 0; dd < DK; dd += 4) {
                const float4 q4 = *reinterpret_cast<const float4*>(&qh[r * DK + dd]);
                s = fmaf(q4.x, kreg[dd + 0], fmaf(q4.y, kreg[dd + 1],
                    fmaf(q4.z, kreg[dd + 2], fmaf(q4.w, kreg[dd + 3], s))));
            }
            s += bt[ri[r * L + lc] * NH + h] + mg[r * L + lc];
            if (lane >= L) s = -INFINITY;

            float m = s;
            #pragma unroll
            for (int off = 32; off > 0; off >>= 1) m = fmaxf(m, __shfl_xor(m, off));
            const float p = __expf(s - m);         // lanes >= L give exp(-inf) = 0
            float sum = p;
            #pragma unroll
            for (int off = 32; off > 0; off >>= 1) sum += __shfl_xor(sum, off);
            const float rs = 1.0f / sum;

            // PV: lanes duplicate across halves; d = lane&31 output column
            float acc = 0.0f;
            #pragma unroll
            for (int kk = 0; kk < L; ++kk) {
                const float pk = __shfl(p, kk);    // readlane broadcast of unnormalized p
                acc = fmaf(pk, vh[kk * DK + d], acc);
            }
            if (lane < DK) ah[r * DK + lane] = acc * rs;
        }
        __syncthreads();

        // ---------------- Phase C: out += attn_h @ wo_h ----------------
        for (int kk = 0; kk < DK; kk += 4) {
            const float* wop = wo + (size_t)(h * DK + kk) * C + t;
            const float w0 = wop[0], w1 = wop[C], w2 = wop[2 * C], w3 = wop[3 * C];
            #pragma unroll
            for (int r = 0; r < L; ++r) {
                const float4 a4 = *reinterpret_cast<const float4*>(&ah[r * DK + kk]);
                oacc[r] = fmaf(a4.x, w0, fmaf(a4.y, w1, fmaf(a4.z, w2, fmaf(a4.w, w3, oacc[r]))));
            }
        }
        __syncthreads(); // ah reused next head
    }

    float* __restrict__ og = out + (size_t)w * (L * C);
    #pragma unroll
    for (int r = 0; r < L; ++r) og[r * C + t] = oacc[r];
}

extern "C" void kernel_launch(void* const* d_in, const int* in_sizes, int n_in,
                              void* d_out, int out_size, void* d_ws, size_t ws_size,
                              hipStream_t stream) {
    const float* x   = (const float*)d_in[0];
    const float* mk  = (const float*)d_in[1];
    const float* wq  = (const float*)d_in[2];
    const float* wk  = (const float*)d_in[3];
    const float* wv  = (const float*)d_in[4];
    const float* wo  = (const float*)d_in[5];
    const float* bt  = (const float*)d_in[6];
    const int*   ri  = (const int*)d_in[7];
    float* out = (float*)d_out;
    (void)n_in; (void)d_ws; (void)ws_size; (void)out_size;

    const int nwin = in_sizes[0] / (L * C);   // 4096
    winattn_fused<<<dim3(nwin), dim3(256), 0, stream>>>(x, mk, wq, wk, wv, wo, bt, ri, out);
}

// Round 2
// 897.742 us; speedup vs baseline: 6.5434x; 6.5434x over previous
//
#include <hip/hip_runtime.h>
#include <math.h>

// WindowAttention, bf16-MFMA fused kernel (fp32 accumulate).
// x:[4096,49,256] mask:[64,49,49] wq/wk/wv/wo:[256,256] bias_table:[169,8] rel_index:[49,49]
// out:[4096,49,256] fp32
//
// One block per window, 256 threads = 4 waves. Wave = 16-row M-stripe (ti = wid) for all GEMMs.
// Per head h (8 heads, serial):
//   qkv GEMM  : q/k/v[:, h*32..] = xb @ W  (A-frags from LDS, B-frags pre-packed in d_ws)
//   scores    : q @ k^T via MFMA, + bias gather + mask, in-register softmax (shfl_xor over 16-lane groups)
//   PV        : P(bf16,unnormalized) @ V (stored transposed), scaled by 1/rowsum after
//   out GEMM  : out += ao_h @ wo[h*32:(h+1)*32, :]  accumulated in 64 f32 VGPRs
// LDS 62.9KB -> 2 blocks/CU.

constexpr int L  = 49;
constexpr int C  = 256;
constexpr int NH = 8;
constexpr int DK = 32;

// LDS row strides (bf16 elements), chosen for 16B-aligned b128 frag reads w/ <=2-way bank aliasing
constexpr int XS = 264;   // xb   [64][264]
constexpr int QS = 40;    // qc,kc[64][40]
constexpr int VS = 72;    // vcT  [32][72]
constexpr int PS = 72;    // pb   [64][72]
constexpr int AS = 40;    // aob  [64][40]

typedef __attribute__((ext_vector_type(8))) short  short8;
typedef __attribute__((ext_vector_type(4))) short  short4v;
typedef __attribute__((ext_vector_type(4))) float  f32x4;
typedef __attribute__((ext_vector_type(4))) unsigned int uint4v;

__device__ inline unsigned short bf16r(float f) {   // RNE f32 -> bf16
    unsigned u = __float_as_uint(f);
    u += 0x7fffu + ((u >> 16) & 1u);
    return (unsigned short)(u >> 16);
}

__device__ inline f32x4 mfma16(short8 a, short8 b, f32x4 c) {
    return __builtin_amdgcn_mfma_f32_16x16x32_bf16(a, b, c, 0, 0, 0);
}

// Fallback B-fragment: gather 8 fp32 (stride 256) + convert. Used only if ws too small.
__device__ inline short8 bfrag_gather(const float* __restrict__ W, int kb, int jb) {
    const int l = threadIdx.x & 63;
    const float* p = W + (size_t)(kb + ((l >> 4) << 3)) * C + jb + (l & 15);
    short8 r;
    #pragma unroll
    for (int e = 0; e < 8; ++e) r[e] = (short)bf16r(p[e * C]);
    return r;
}

// Pre-pack all weights into MFMA B-fragments (bf16), one uint4 (=8 bf16 = one lane's frag) per thread.
// Layout (uint4 units): wq frags [0,8192) idx=((h*8+ks)*2+tj)*64+lane ; wk +8192 ; wv +16384 ;
//                       wo [24576,32768) idx=(h*16+tj)*64+lane
__global__ __launch_bounds__(256)
void pack_weights(const float* __restrict__ wq, const float* __restrict__ wk,
                  const float* __restrict__ wv, const float* __restrict__ wo,
                  uint4v* __restrict__ ws)
{
    const int gid = blockIdx.x * 256 + threadIdx.x;   // 0..32767
    const int m   = gid >> 13;                        // 0..3
    const int rem = gid & 8191;
    int row0, col;
    const float* W;
    if (m < 3) {
        const int h  = rem >> 10;
        const int r2 = rem & 1023;
        const int ks = r2 >> 7;
        const int tj = (r2 >> 6) & 1;
        const int ln = r2 & 63;
        col  = h * DK + tj * 16 + (ln & 15);
        row0 = ks * 32 + ((ln >> 4) << 3);
        W = (m == 0) ? wq : (m == 1) ? wk : wv;
    } else {
        const int h  = rem >> 10;
        const int tj = (rem >> 6) & 15;
        const int ln = rem & 63;
        col  = tj * 16 + (ln & 15);
        row0 = h * DK + ((ln >> 4) << 3);
        W = wo;
    }
    unsigned short b[8];
    #pragma unroll
    for (int e = 0; e < 8; ++e) b[e] = bf16r(W[(size_t)(row0 + e) * C + col]);
    uint4v u;
    u.x = (unsigned)b[0] | ((unsigned)b[1] << 16);
    u.y = (unsigned)b[2] | ((unsigned)b[3] << 16);
    u.z = (unsigned)b[4] | ((unsigned)b[5] << 16);
    u.w = (unsigned)b[6] | ((unsigned)b[7] << 16);
    ws[gid] = u;
}

template<bool PACKED>
__global__ __launch_bounds__(256, 2)
void winattn_mfma(const float* __restrict__ x,  const float* __restrict__ msk,
                  const float* __restrict__ wq, const float* __restrict__ wk,
                  const float* __restrict__ wv, const float* __restrict__ wo,
                  const float* __restrict__ bt, const int* __restrict__ ri,
                  const uint4v* __restrict__ wpk, float* __restrict__ out)
{
    __shared__ short xb [64 * XS];   // x, bf16, rows>=49 zeroed
    __shared__ short qc [64 * QS];   // q head chunk [token][dk]
    __shared__ short kc [64 * QS];   // k head chunk [token][dk]
    __shared__ short vcT[DK * VS];   // v head chunk transposed [dk][token]
    __shared__ short pb [64 * PS];   // P (unnormalized softmax numerator) [token q][token k]
    __shared__ short aob[64 * AS];   // attn output head chunk [token][dk]

    const int t    = threadIdx.x;
    const int w    = blockIdx.x;
    const int lane = t & 63;
    const int wid  = t >> 6;       // wave id = M-stripe (ti)
    const int lo   = lane & 15;
    const int hi   = lane >> 4;

    const float* __restrict__ xg = x   + (size_t)w * (L * C);
    const float* __restrict__ mg = msk + (size_t)(w & 63) * (L * L);
    const short8* __restrict__ wp8 = reinterpret_cast<const short8*>(wpk);

    // ---- stage x -> bf16 LDS (rows >= 49 zero) ----
    #pragma unroll
    for (int j = 0; j < 16; ++j) {
        const int idx = t + 256 * j;          // float4 index over [64][64]
        const int r = idx >> 6;
        const int c = (idx & 63) * 4;
        short4v s4 = {0, 0, 0, 0};
        if (r < L) {
            const float4 xv = *reinterpret_cast<const float4*>(xg + r * C + c);
            s4.x = (short)bf16r(xv.x); s4.y = (short)bf16r(xv.y);
            s4.z = (short)bf16r(xv.z); s4.w = (short)bf16r(xv.w);
        }
        *reinterpret_cast<short4v*>(&xb[r * XS + c]) = s4;
    }
    __syncthreads();

    // ---- hoist mask values + prescaled bias indices (same (r,ck) every head) ----
    int   bidx[4][4];
    float mval[4][4];
    #pragma unroll
    for (int tj = 0; tj < 4; ++tj)
        #pragma unroll
        for (int rg = 0; rg < 4; ++rg) {
            const int r  = wid * 16 + hi * 4 + rg;
            const int ck = tj * 16 + lo;
            const int rr = (r  < L) ? r  : L - 1;
            const int cc = (ck < L) ? ck : L - 1;
            bidx[tj][rg] = ri[rr * L + cc] * NH;
            mval[tj][rg] = mg[rr * L + cc];
        }

    f32x4 oc[16];                       // out accumulator: rows = wave stripe, cols = 256
    #pragma unroll
    for (int i = 0; i < 16; ++i) oc[i] = (f32x4){0.f, 0.f, 0.f, 0.f};

    const f32x4 zf = (f32x4){0.f, 0.f, 0.f, 0.f};

    for (int h = 0; h < NH; ++h) {
        // ================= qkv GEMM for head h =================
        f32x4 cq[2], ck_[2], cv[2];
        #pragma unroll
        for (int tj = 0; tj < 2; ++tj) { cq[tj] = zf; ck_[tj] = zf; cv[tj] = zf; }

        #pragma unroll
        for (int ks = 0; ks < 8; ++ks) {
            const short8 a = *reinterpret_cast<const short8*>(
                &xb[(wid * 16 + lo) * XS + ks * 32 + hi * 8]);
            #pragma unroll
            for (int tj = 0; tj < 2; ++tj) {
                short8 bq, bk, bv;
                if (PACKED) {
                    const int base = ((h * 8 + ks) * 2 + tj) * 64 + lane;
                    bq = wp8[base]; bk = wp8[8192 + base]; bv = wp8[16384 + base];
                } else {
                    bq = bfrag_gather(wq, ks * 32, h * DK + tj * 16);
                    bk = bfrag_gather(wk, ks * 32, h * DK + tj * 16);
                    bv = bfrag_gather(wv, ks * 32, h * DK + tj * 16);
                }
                cq[tj]  = mfma16(a, bq, cq[tj]);
                ck_[tj] = mfma16(a, bk, ck_[tj]);
                cv[tj]  = mfma16(a, bv, cv[tj]);
            }
        }
        // write q,k row-major [token][dk]; v transposed [dk][token]
        #pragma unroll
        for (int tj = 0; tj < 2; ++tj) {
            #pragma unroll
            for (int rg = 0; rg < 4; ++rg) {
                const int row = wid * 16 + hi * 4 + rg;
                const int col = tj * 16 + lo;
                qc[row * QS + col] = (short)bf16r(cq[tj][rg]);
                kc[row * QS + col] = (short)bf16r(ck_[tj][rg]);
            }
            short4v vv;
            vv.x = (short)bf16r(cv[tj][0]); vv.y = (short)bf16r(cv[tj][1]);
            vv.z = (short)bf16r(cv[tj][2]); vv.w = (short)bf16r(cv[tj][3]);
            *reinterpret_cast<short4v*>(&vcT[(tj * 16 + lo) * VS + wid * 16 + hi * 4]) = vv;
        }
        __syncthreads();   // qc/kc/vcT visible to all waves

        // ================= scores + softmax =================
        const short8 qa = *reinterpret_cast<const short8*>(
            &qc[(wid * 16 + lo) * QS + hi * 8]);
        f32x4 sc[4];
        #pragma unroll
        for (int tj = 0; tj < 4; ++tj) {
            const short8 kb = *reinterpret_cast<const short8*>(
                &kc[(tj * 16 + lo) * QS + hi * 8]);
            sc[tj] = mfma16(qa, kb, zf);
        }
        // + bias + mask, key-padding mask
        #pragma unroll
        for (int tj = 0; tj < 4; ++tj)
            #pragma unroll
            for (int rg = 0; rg < 4; ++rg) {
                float s = sc[tj][rg] + bt[bidx[tj][rg] + h] + mval[tj][rg];
                if (tj * 16 + lo >= L) s = -1e30f;
                sc[tj][rg] = s;
            }
        // row max / sum via butterfly over the 16-lane column group
        float rinv[4];
        #pragma unroll
        for (int rg = 0; rg < 4; ++rg) {
            float m = fmaxf(fmaxf(sc[0][rg], sc[1][rg]), fmaxf(sc[2][rg], sc[3][rg]));
            #pragma unroll
            for (int off = 1; off < 16; off <<= 1) m = fmaxf(m, __shfl_xor(m, off));
            float s0 = 0.f;
            #pragma unroll
            for (int tj = 0; tj < 4; ++tj) {
                const float p = __expf(sc[tj][rg] - m);
                sc[tj][rg] = p;
                s0 += p;
            }
            #pragma unroll
            for (int off = 1; off < 16; off <<= 1) s0 += __shfl_xor(s0, off);
            rinv[rg] = 1.0f / s0;
        }
        // write unnormalized P (bf16)
        #pragma unroll
        for (int tj = 0; tj < 4; ++tj)
            #pragma unroll
            for (int rg = 0; rg < 4; ++rg)
                pb[(wid * 16 + hi * 4 + rg) * PS + tj * 16 + lo] = (short)bf16r(sc[tj][rg]);

        // ================= PV ================= (pb rows self-written; vcT covered by barrier)
        f32x4 pv[2];
        #pragma unroll
        for (int tj = 0; tj < 2; ++tj) pv[tj] = zf;
        #pragma unroll
        for (int ksp = 0; ksp < 2; ++ksp) {
            const short8 pa = *reinterpret_cast<const short8*>(
                &pb[(wid * 16 + lo) * PS + ksp * 32 + hi * 8]);
            #pragma unroll
            for (int tj = 0; tj < 2; ++tj) {
                const short8 vb = *reinterpret_cast<const short8*>(
                    &vcT[(tj * 16 + lo) * VS + ksp * 32 + hi * 8]);
                pv[tj] = mfma16(pa, vb, pv[tj]);
            }
        }
        // normalize rows and write ao_h
        #pragma unroll
        for (int tj = 0; tj < 2; ++tj)
            #pragma unroll
            for (int rg = 0; rg < 4; ++rg)
                aob[(wid * 16 + hi * 4 + rg) * AS + tj * 16 + lo] =
                    (short)bf16r(pv[tj][rg] * rinv[rg]);

        // ================= out += ao_h @ wo_h ================= (aob stripe self-written)
        const short8 aa = *reinterpret_cast<const short8*>(
            &aob[(wid * 16 + lo) * AS + hi * 8]);
        #pragma unroll
        for (int tj = 0; tj < 16; ++tj) {
            short8 bo;
            if (PACKED) bo = wp8[24576 + (h * 16 + tj) * 64 + lane];
            else        bo = bfrag_gather(wo, h * DK, tj * 16);
            oc[tj] = mfma16(aa, bo, oc[tj]);
        }
        __syncthreads();   // all reads of qc/kc/vcT done before next head overwrites
    }

    // ---- store ----
    float* __restrict__ og = out + (size_t)w * (L * C);
    #pragma unroll
    for (int tj = 0; tj < 16; ++tj)
        #pragma unroll
        for (int rg = 0; rg < 4; ++rg) {
            const int row = wid * 16 + hi * 4 + rg;
            if (row < L) og[row * C + tj * 16 + lo] = oc[tj][rg];
        }
}

extern "C" void kernel_launch(void* const* d_in, const int* in_sizes, int n_in,
                              void* d_out, int out_size, void* d_ws, size_t ws_size,
                              hipStream_t stream) {
    const float* x   = (const float*)d_in[0];
    const float* mk  = (const float*)d_in[1];
    const float* wq  = (const float*)d_in[2];
    const float* wk  = (const float*)d_in[3];
    const float* wv  = (const float*)d_in[4];
    const float* wo  = (const float*)d_in[5];
    const float* bt  = (const float*)d_in[6];
    const int*   ri  = (const int*)d_in[7];
    float* out = (float*)d_out;
    (void)n_in; (void)out_size;

    const int nwin = in_sizes[0] / (L * C);   // 4096
    const bool packed = ws_size >= (size_t)32768 * 16;

    if (packed) {
        pack_weights<<<dim3(128), dim3(256), 0, stream>>>(wq, wk, wv, wo, (uint4v*)d_ws);
        winattn_mfma<true><<<dim3(nwin), dim3(256), 0, stream>>>(
            x, mk, wq, wk, wv, wo, bt, ri, (const uint4v*)d_ws, out);
    } else {
        winattn_mfma<false><<<dim3(nwin), dim3(256), 0, stream>>>(
            x, mk, wq, wk, wv, wo, bt, ri, nullptr, out);
    }
}